// Round 2
// baseline (511.358 us; speedup 1.0000x reference)
//
#include <hip/hip_runtime.h>
#include <cmath>

#define NB 1024   // batches
#define NN 1024   // rows
#define MM 64     // cols
#define NT 256    // threads per block
#define NSL 8     // slices per batch (rows per slice = NN/NSL = 128)
#define RPS (NN / NSL)

// Block-wide sum over 256 threads (4 waves).
__device__ __forceinline__ float block_sum(float v, float* s_tmp) {
    #pragma unroll
    for (int off = 32; off > 0; off >>= 1) v += __shfl_xor(v, off, 64);
    if ((threadIdx.x & 63) == 0) s_tmp[threadIdx.x >> 6] = v;
    __syncthreads();
    float r = s_tmp[0] + s_tmp[1] + s_tmp[2] + s_tmp[3];
    __syncthreads();
    return r;
}

__device__ __forceinline__ float block_max(float v, float* s_tmp) {
    #pragma unroll
    for (int off = 32; off > 0; off >>= 1) v = fmaxf(v, __shfl_xor(v, off, 64));
    if ((threadIdx.x & 63) == 0) s_tmp[threadIdx.x >> 6] = v;
    __syncthreads();
    float r = fmaxf(fmaxf(s_tmp[0], s_tmp[1]), fmaxf(s_tmp[2], s_tmp[3]));
    __syncthreads();
    return r;
}

// Kernel 1: cosine-similarity scores, 8 blocks per batch, 128 rows each.
// score(b,n) -> wbuf[b*bs + n*rs]
__global__ void __launch_bounds__(NT) k_scores(
    const float* __restrict__ memory,
    const float* __restrict__ k,
    const float* __restrict__ beta,
    float* __restrict__ wbuf, long bs, long rs)
{
    __shared__ float s_k[MM];
    __shared__ float s_tmp[4];

    const int b  = blockIdx.x >> 3;
    const int sl = blockIdx.x & 7;
    const int t  = threadIdx.x;
    const int cg = t & 15;   // 16 threads per row
    const int rg = t >> 4;   // 16 rows per iteration

    if (t < MM) s_k[t] = k[b * MM + t] + 1e-16f;
    __syncthreads();
    float kq = (t < MM) ? s_k[t] * s_k[t] : 0.0f;
    const float kden = fmaxf(sqrtf(block_sum(kq, s_tmp)), 1e-8f);
    const float bet  = beta[b];
    const float4 k4  = ((const float4*)s_k)[cg];

    const float* memb = memory + (size_t)b * NN * MM;
    const int n0 = sl * RPS;
    #pragma unroll
    for (int it = 0; it < RPS / 16; ++it) {
        int n = n0 + it * 16 + rg;
        float4 m4 = *(const float4*)(memb + n * MM + 4 * cg);
        float ex = m4.x + 1e-16f, ey = m4.y + 1e-16f;
        float ez = m4.z + 1e-16f, ew = m4.w + 1e-16f;
        float d = ex * k4.x + ey * k4.y + ez * k4.z + ew * k4.w;
        float q = ex * ex + ey * ey + ez * ez + ew * ew;
        #pragma unroll
        for (int off = 8; off > 0; off >>= 1) {
            d += __shfl_xor(d, off, 64);
            q += __shfl_xor(q, off, 64);
        }
        if (cg == 0) {
            float denom = fmaxf(sqrtf(q), 1e-8f) * kden;
            wbuf[(size_t)b * bs + (size_t)n * rs] = bet * d / denom;
        }
    }
}

// Kernel 2: softmax + interpolate + shift + sharpen. One block per batch.
// Reads scores from wbuf, writes final w back to wbuf. Zeroes read row of out.
__global__ void __launch_bounds__(NT) k_weights(
    const float* __restrict__ g,
    const float* __restrict__ s,
    const float* __restrict__ gamma,
    const float* __restrict__ w_prev,
    float* __restrict__ wbuf, long bs, long rs,
    float* __restrict__ out)
{
    __shared__ float s_wg[NN];
    __shared__ float s_w[NN];
    __shared__ float s_tmp[4];

    const int b = blockIdx.x;
    const int t = threadIdx.x;
    float* wb = wbuf + (size_t)b * bs;

    float sc0 = wb[(size_t)(t      ) * rs];
    float sc1 = wb[(size_t)(t + 256) * rs];
    float sc2 = wb[(size_t)(t + 512) * rs];
    float sc3 = wb[(size_t)(t + 768) * rs];
    float mx = block_max(fmaxf(fmaxf(sc0, sc1), fmaxf(sc2, sc3)), s_tmp);
    float e0 = __expf(sc0 - mx), e1 = __expf(sc1 - mx);
    float e2 = __expf(sc2 - mx), e3 = __expf(sc3 - mx);
    float inv_esum = 1.0f / block_sum(e0 + e1 + e2 + e3, s_tmp);

    const float gb = g[b], omg = 1.0f - gb;
    s_wg[t]       = gb * e0 * inv_esum + omg * w_prev[b * NN + t];
    s_wg[t + 256] = gb * e1 * inv_esum + omg * w_prev[b * NN + t + 256];
    s_wg[t + 512] = gb * e2 * inv_esum + omg * w_prev[b * NN + t + 512];
    s_wg[t + 768] = gb * e3 * inv_esum + omg * w_prev[b * NN + t + 768];
    __syncthreads();

    const float s0 = s[b * 3 + 0], s1 = s[b * 3 + 1], s2 = s[b * 3 + 2];
    const float gam = gamma[b];
    float wpart = 0.0f;
    #pragma unroll
    for (int j = 0; j < 4; ++j) {
        int n  = t + j * 256;
        int nm = (n == 0) ? NN - 1 : n - 1;
        int np = (n == NN - 1) ? 0 : n + 1;
        float wh = s0 * s_wg[nm] + s1 * s_wg[n] + s2 * s_wg[np];
        float w  = powf(wh, gam);
        s_w[n] = w;
        wpart += w;
    }
    float winv = 1.0f / (block_sum(wpart, s_tmp) + 1e-16f);
    #pragma unroll
    for (int j = 0; j < 4; ++j) {
        int n = t + j * 256;
        wb[(size_t)n * rs] = s_w[n] * winv;
    }
    // zero the read row (d_out is poisoned 0xAA; kernel 3 atomically accumulates)
    if (t < MM) out[(size_t)b * (NN + 1) * MM + t] = 0.0f;
}

// Kernel 3: erase/add update + partial read sums. 8 blocks per batch.
__global__ void __launch_bounds__(NT) k_update(
    const float* __restrict__ memory,
    const float* __restrict__ e,
    const float* __restrict__ a,
    const float* __restrict__ wbuf, long bs, long rs,
    float* __restrict__ out)
{
    __shared__ float  s_w[RPS];
    __shared__ float4 s_red[NT];

    const int b  = blockIdx.x >> 3;
    const int sl = blockIdx.x & 7;
    const int t  = threadIdx.x;
    const int cg = t & 15;
    const int rg = t >> 4;
    const int n0 = sl * RPS;

    if (t < RPS) s_w[t] = wbuf[(size_t)b * bs + (size_t)(n0 + t) * rs];
    __syncthreads();

    const float* memb = memory + (size_t)b * NN * MM;
    float*       outb = out    + (size_t)b * (NN + 1) * MM;
    const float4 e4 = *(const float4*)(e + b * MM + 4 * cg);
    const float4 a4 = *(const float4*)(a + b * MM + 4 * cg);

    float4 acc = make_float4(0.f, 0.f, 0.f, 0.f);
    #pragma unroll
    for (int it = 0; it < RPS / 16; ++it) {
        int nl = it * 16 + rg;          // local row in slice
        int n  = n0 + nl;
        float4 m4 = *(const float4*)(memb + n * MM + 4 * cg);
        float wn = s_w[nl];
        acc.x += wn * m4.x; acc.y += wn * m4.y;
        acc.z += wn * m4.z; acc.w += wn * m4.w;
        float4 o;
        o.x = m4.x * (1.0f - wn * e4.x) + wn * a4.x;
        o.y = m4.y * (1.0f - wn * e4.y) + wn * a4.y;
        o.z = m4.z * (1.0f - wn * e4.z) + wn * a4.z;
        o.w = m4.w * (1.0f - wn * e4.w) + wn * a4.w;
        *(float4*)(outb + (size_t)(n + 1) * MM + 4 * cg) = o;
    }

    s_red[t] = acc;
    __syncthreads();
    if (t < 16) {
        float4 r = make_float4(0.f, 0.f, 0.f, 0.f);
        #pragma unroll
        for (int gi = 0; gi < 16; ++gi) {
            float4 v = s_red[gi * 16 + t];
            r.x += v.x; r.y += v.y; r.z += v.z; r.w += v.w;
        }
        atomicAdd(outb + 4 * t + 0, r.x);
        atomicAdd(outb + 4 * t + 1, r.y);
        atomicAdd(outb + 4 * t + 2, r.z);
        atomicAdd(outb + 4 * t + 3, r.w);
    }
}

extern "C" void kernel_launch(void* const* d_in, const int* in_sizes, int n_in,
                              void* d_out, int out_size, void* d_ws, size_t ws_size,
                              hipStream_t stream) {
    const float* memory = (const float*)d_in[0];
    const float* k      = (const float*)d_in[1];
    const float* beta   = (const float*)d_in[2];
    const float* g      = (const float*)d_in[3];
    const float* s      = (const float*)d_in[4];
    const float* gamma  = (const float*)d_in[5];
    const float* w_prev = (const float*)d_in[6];
    const float* e      = (const float*)d_in[7];
    const float* a      = (const float*)d_in[8];
    float* out = (float*)d_out;

    // weight buffer: d_ws if it fits (4 MB), else stash in col 0 of out rows 1..N
    const size_t need = (size_t)NB * NN * sizeof(float);
    float* wbuf; long bs, rs;
    if (ws_size >= need) {
        wbuf = (float*)d_ws; bs = NN; rs = 1;
    } else {
        wbuf = out + MM; bs = (long)(NN + 1) * MM; rs = MM;
    }

    k_scores <<<NB * NSL, NT, 0, stream>>>(memory, k, beta, wbuf, bs, rs);
    k_weights<<<NB,       NT, 0, stream>>>(g, s, gamma, w_prev, wbuf, bs, rs, out);
    k_update <<<NB * NSL, NT, 0, stream>>>(memory, e, a, wbuf, bs, rs, out);
}